// Round 1
// 64.143 us; speedup vs baseline: 1.1590x; 1.1590x over previous
//
#include <hip/hip_runtime.h>
#include <hip/hip_bf16.h>

#define B_DIM 512
#define D_DIM 512
#define O_DIM 512
#define DCH   128          // d-columns staged per chunk
#define NCH   (D_DIM/DCH)  // 4 chunks

// logits[b,o] = sum_d [ (-ic)*x^2 + (2*mu*ic)*x ] - sum_d mu^2*ic
//            = ([x^2 | x] @ [-ic | 2*mu*ic]^T)[b,o] - c[o]
// Single kernel: grid 256 = (ob 0..15) x (bb 0..15), 32x32 output tile per
// block, K' = 2*512 = 1024 fully inside the block via mfma_f32_16x16x32_bf16.
// No workspace, no reduce kernel, no atomics, deterministic.
// LDS granule = 8 bf16 (16B); XOR-swizzle granule index with (row&7) so both
// ds_write_b128 staging and per-fragment ds_read_b128 are >=2-way max (free).

typedef __attribute__((ext_vector_type(8))) short short8;
typedef __attribute__((ext_vector_type(4))) float f32x4;

__device__ __forceinline__ short f2bf(float f) {
    union { __hip_bfloat16 h; unsigned short u; } cv;
    cv.h = __float2bfloat16(f);
    return (short)cv.u;
}

__global__ __launch_bounds__(256)
void gda_mfma(const float* __restrict__ x,
              const float* __restrict__ mu,
              const float* __restrict__ ic,
              float* __restrict__ out)
{
    // [32 rows][32 granules of 8 bf16] each; granules 0..15 = first operand
    // half (x^2 / -ic), granules 16..31 = second half (x / 2*mu*ic).
    __shared__ unsigned short A_lds[32 * 256];   // 16 KB  (b-rows)
    __shared__ unsigned short B_lds[32 * 256];   // 16 KB  (o-rows)
    __shared__ float          c_part[32 * 8];    //  1 KB  (mu^2*ic partials)
    __shared__ float          c_o[32];

    const int tid = threadIdx.x;
    const int bid = blockIdx.x;
    const int b0 = (bid & 15) * 32;
    const int o0 = (bid >> 4) * 32;

    // staging decomposition: 256 threads -> (row 0..31) x (u 0..7), 2 units each
    const int srow = tid >> 3;
    const int su   = tid & 7;

    // wave decomposition: 4 waves, one 16x16 output quadrant each
    const int w    = tid >> 6;
    const int lane = tid & 63;
    const int wr   = w >> 1;          // A-row quadrant
    const int wc   = w & 1;           // B-col quadrant
    const int fcol = lane & 15;       // fragment row (A) / col (B) / col (D)
    const int fk   = lane >> 4;       // 0..3 k-subgroup

    const int rowA = wr * 16 + fcol;
    const int rowB = wc * 16 + fcol;
    const int swA7 = rowA & 7;
    const int swB7 = rowB & 7;

    float creg = 0.0f;
    f32x4 acc = {0.0f, 0.0f, 0.0f, 0.0f};

    for (int ch = 0; ch < NCH; ++ch) {
        const int d0 = ch * DCH;

        // ---- stage: f32 global -> fused transform -> bf16 LDS ----
#pragma unroll
        for (int half = 0; half < 2; ++half) {
            const int uu  = su + half * 8;        // unit/granule 0..15
            const int swz = uu ^ (srow & 7);
            const int dd  = d0 + uu * 8;

            {   // x unit -> x^2 (granule uu), x (granule 16+uu)
                const float4 p = *(const float4*)&x[(b0 + srow) * D_DIM + dd];
                const float4 q = *(const float4*)&x[(b0 + srow) * D_DIM + dd + 4];
                const float v[8] = {p.x, p.y, p.z, p.w, q.x, q.y, q.z, q.w};
                short8 s2, s1;
#pragma unroll
                for (int e = 0; e < 8; ++e) {
                    s2[e] = f2bf(v[e] * v[e]);
                    s1[e] = f2bf(v[e]);
                }
                *(short8*)&A_lds[(srow * 32 + swz) * 8]      = s2;
                *(short8*)&A_lds[(srow * 32 + 16 + swz) * 8] = s1;
            }
            {   // mu/ic unit -> -ic (granule uu), 2*mu*ic (granule 16+uu)
                const int rbase = (o0 + srow) * D_DIM + dd;
                const float4 m0 = *(const float4*)&mu[rbase];
                const float4 m1 = *(const float4*)&mu[rbase + 4];
                const float4 c0 = *(const float4*)&ic[rbase];
                const float4 c1 = *(const float4*)&ic[rbase + 4];
                const float mv[8] = {m0.x, m0.y, m0.z, m0.w, m1.x, m1.y, m1.z, m1.w};
                const float cf[8] = {c0.x, c0.y, c0.z, c0.w, c1.x, c1.y, c1.z, c1.w};
                short8 sa, sb;
#pragma unroll
                for (int e = 0; e < 8; ++e) {
                    sa[e] = f2bf(-cf[e]);
                    sb[e] = f2bf(2.0f * mv[e] * cf[e]);
                    creg  = fmaf(mv[e] * mv[e], cf[e], creg);
                }
                *(short8*)&B_lds[(srow * 32 + swz) * 8]      = sa;
                *(short8*)&B_lds[(srow * 32 + 16 + swz) * 8] = sb;
            }
        }
        __syncthreads();

        // ---- MFMA: K = 256 per chunk (128 x^2-terms + 128 x-terms) ----
#pragma unroll
        for (int ks = 0; ks < 8; ++ks) {
            const int g  = ks * 4 + fk;                    // granule index
            const short8 av = *(const short8*)&A_lds[(rowA * 32 + (g ^ swA7)) * 8];
            const short8 bv = *(const short8*)&B_lds[(rowB * 32 + (g ^ swB7)) * 8];
            acc = __builtin_amdgcn_mfma_f32_16x16x32_bf16(av, bv, acc, 0, 0, 0);
        }
        __syncthreads();   // safe to overwrite LDS next chunk
    }

    // ---- per-o constant c[o] = sum_d mu^2*ic (fp32 exact) ----
    c_part[srow * 8 + su] = creg;
    __syncthreads();
    if (tid < 32) {
        float s = 0.0f;
#pragma unroll
        for (int q = 0; q < 8; ++q) s += c_part[tid * 8 + q];
        c_o[tid] = s;
    }
    __syncthreads();

    // ---- epilogue: D frag (col = lane&15, row = (lane>>4)*4 + r) ----
#pragma unroll
    for (int r = 0; r < 4; ++r) {
        const int row = wr * 16 + fk * 4 + r;
        const int col = wc * 16 + fcol;
        out[(b0 + row) * O_DIM + o0 + col] = acc[r] - c_o[col];
    }
}

extern "C" void kernel_launch(void* const* d_in, const int* in_sizes, int n_in,
                              void* d_out, int out_size, void* d_ws, size_t ws_size,
                              hipStream_t stream) {
    const float* x  = (const float*)d_in[0];
    const float* mu = (const float*)d_in[1];
    const float* ic = (const float*)d_in[2];
    float* out = (float*)d_out;

    gda_mfma<<<dim3(256), dim3(256), 0, stream>>>(x, mu, ic, out);
}

// Round 2
// 62.222 us; speedup vs baseline: 1.1948x; 1.0309x over previous
//
#include <hip/hip_runtime.h>
#include <hip/hip_bf16.h>

#define B_DIM 512
#define D_DIM 512
#define O_DIM 512

// logits[b,o] = sum_d [ (-ic)*x^2 + (2*mu*ic)*x ] - sum_d mu^2*ic
//            = ([x^2 | x] @ [-ic | 2*mu*ic]^T)[b,o] - c[o]
//
// Grid 256 = (ob 0..15) x (bb 0..15); block 512 threads = 8 waves.
// Whole K' = 1024 staged once into LDS (A 64KB + B 64KB), single load phase.
// Each wave: 2x2 register-blocked 32x32 output tile over its K'-eighth
// (granules w*16 .. w*16+15), 16 MFMAs / 16 ds_read_b128 per lane.
// 8-way K-partial reduce through LDS (aliased onto A panel), f32-exact
// per-o constant, deterministic, no atomics, no workspace.

typedef __attribute__((ext_vector_type(8))) short short8;
typedef __attribute__((ext_vector_type(4))) float f32x4;

__device__ __forceinline__ short f2bf(float f) {
    union { __hip_bfloat16 h; unsigned short u; } cv;
    cv.h = __float2bfloat16(f);
    return (short)cv.u;
}

__device__ __forceinline__ short8 pack8(float a0, float a1, float a2, float a3,
                                        float a4, float a5, float a6, float a7) {
    short8 r;
    r[0] = f2bf(a0); r[1] = f2bf(a1); r[2] = f2bf(a2); r[3] = f2bf(a3);
    r[4] = f2bf(a4); r[5] = f2bf(a5); r[6] = f2bf(a6); r[7] = f2bf(a7);
    return r;
}

// position of K'-granule g (0..127) within a row: XOR low-4 bits with row&15
// -> quarter-wave conflict-free for both staging writes and fragment reads.
__device__ __forceinline__ int gpos(int g, int row) {
    return (g & ~15) | ((g & 15) ^ (row & 15));
}

__global__ __launch_bounds__(512, 2)
void gda_mfma(const float* __restrict__ x,
              const float* __restrict__ mu,
              const float* __restrict__ ic,
              float* __restrict__ out)
{
    // [32 rows][128 granules of 8 bf16]; granules 0..63 = x^2 / -ic section,
    // 64..127 = x / 2*mu*ic section.
    __shared__ __align__(16) unsigned short A_lds[32 * 128 * 8];  // 64 KB
    __shared__ __align__(16) unsigned short B_lds[32 * 128 * 8];  // 64 KB
    __shared__ float c_part[512];
    __shared__ float c_o[32];

    const int tid = threadIdx.x;
    const int bid = blockIdx.x;
    const int b0 = (bid & 15) * 32;
    const int o0 = (bid >> 4) * 32;

    // ---- stage: full K', one pass; thread = (row 0..31) x (unit 0..15) ----
    const int srow = tid >> 4;
    const int su   = tid & 15;

    float creg = 0.0f;
#pragma unroll
    for (int t = 0; t < 4; ++t) {
        const int g  = su + t * 16;          // d-granule 0..63
        const int dd = g * 8;
        const float4 p  = *(const float4*)&x [(b0 + srow) * D_DIM + dd];
        const float4 q  = *(const float4*)&x [(b0 + srow) * D_DIM + dd + 4];
        const float4 m0 = *(const float4*)&mu[(o0 + srow) * D_DIM + dd];
        const float4 m1 = *(const float4*)&mu[(o0 + srow) * D_DIM + dd + 4];
        const float4 c0 = *(const float4*)&ic[(o0 + srow) * D_DIM + dd];
        const float4 c1 = *(const float4*)&ic[(o0 + srow) * D_DIM + dd + 4];

        const int plo = gpos(g, srow);       // x^2 / -ic granule
        const int phi = plo + 64;            // x / 2*mu*ic granule

        *(short8*)&A_lds[(srow * 128 + plo) * 8] =
            pack8(p.x*p.x, p.y*p.y, p.z*p.z, p.w*p.w,
                  q.x*q.x, q.y*q.y, q.z*q.z, q.w*q.w);
        *(short8*)&A_lds[(srow * 128 + phi) * 8] =
            pack8(p.x, p.y, p.z, p.w, q.x, q.y, q.z, q.w);
        *(short8*)&B_lds[(srow * 128 + plo) * 8] =
            pack8(-c0.x, -c0.y, -c0.z, -c0.w, -c1.x, -c1.y, -c1.z, -c1.w);
        *(short8*)&B_lds[(srow * 128 + phi) * 8] =
            pack8(2.0f*m0.x*c0.x, 2.0f*m0.y*c0.y, 2.0f*m0.z*c0.z, 2.0f*m0.w*c0.w,
                  2.0f*m1.x*c1.x, 2.0f*m1.y*c1.y, 2.0f*m1.z*c1.z, 2.0f*m1.w*c1.w);

        creg = fmaf(m0.x*m0.x, c0.x, creg);
        creg = fmaf(m0.y*m0.y, c0.y, creg);
        creg = fmaf(m0.z*m0.z, c0.z, creg);
        creg = fmaf(m0.w*m0.w, c0.w, creg);
        creg = fmaf(m1.x*m1.x, c1.x, creg);
        creg = fmaf(m1.y*m1.y, c1.y, creg);
        creg = fmaf(m1.z*m1.z, c1.z, creg);
        creg = fmaf(m1.w*m1.w, c1.w, creg);
    }
    c_part[tid] = creg;
    __syncthreads();

    // per-o constant: c_o[o] = sum_d mu^2*ic (f32 exact, fixed order)
    if (tid < 32) {
        float s = 0.0f;
#pragma unroll
        for (int qq = 0; qq < 16; ++qq) s += c_part[tid * 16 + qq];
        c_o[tid] = s;
    }

    // ---- MFMA: wave w owns K'-granules [w*16, w*16+16), 2x2 x 16x16 tile ----
    const int w    = tid >> 6;
    const int lane = tid & 63;
    const int fc   = lane & 15;              // fragment row (A) / row (B) / col (D)
    const int fk   = lane >> 4;              // k-subgroup 0..3

    f32x4 acc[2][2];
#pragma unroll
    for (int i = 0; i < 2; ++i)
#pragma unroll
        for (int j = 0; j < 2; ++j)
            acc[i][j] = (f32x4){0.0f, 0.0f, 0.0f, 0.0f};

#pragma unroll
    for (int m = 0; m < 4; ++m) {
        const int g = w * 16 + m * 4 + fk;
        const short8 a0 = *(const short8*)&A_lds[( fc       * 128 + gpos(g, fc     )) * 8];
        const short8 a1 = *(const short8*)&A_lds[((16 + fc) * 128 + gpos(g, 16 + fc)) * 8];
        const short8 bv0 = *(const short8*)&B_lds[( fc       * 128 + gpos(g, fc     )) * 8];
        const short8 bv1 = *(const short8*)&B_lds[((16 + fc) * 128 + gpos(g, 16 + fc)) * 8];
        acc[0][0] = __builtin_amdgcn_mfma_f32_16x16x32_bf16(a0, bv0, acc[0][0], 0, 0, 0);
        acc[0][1] = __builtin_amdgcn_mfma_f32_16x16x32_bf16(a0, bv1, acc[0][1], 0, 0, 0);
        acc[1][0] = __builtin_amdgcn_mfma_f32_16x16x32_bf16(a1, bv0, acc[1][0], 0, 0, 0);
        acc[1][1] = __builtin_amdgcn_mfma_f32_16x16x32_bf16(a1, bv1, acc[1][1], 0, 0, 0);
    }
    __syncthreads();                          // all LDS reads done

    // ---- 8-way K-partial reduce via LDS (aliased onto A panel) ----
    float* part = (float*)A_lds;              // 8 * 1056 floats = 33 KB < 64 KB
#pragma unroll
    for (int i = 0; i < 2; ++i)
#pragma unroll
        for (int j = 0; j < 2; ++j)
#pragma unroll
            for (int r = 0; r < 4; ++r) {
                const int lrow = i * 16 + fk * 4 + r;
                const int lcol = j * 16 + fc;
                part[w * 1056 + lrow * 33 + lcol] = acc[i][j][r];
            }
    __syncthreads();

    // ---- final: fixed-order sum over 8 K-partials, subtract c, store ----
#pragma unroll
    for (int p = 0; p < 2; ++p) {
        const int idx  = p * 512 + tid;
        const int lrow = idx >> 5;
        const int lcol = idx & 31;
        float s = 0.0f;
#pragma unroll
        for (int ww = 0; ww < 8; ++ww) s += part[ww * 1056 + lrow * 33 + lcol];
        out[(b0 + lrow) * O_DIM + o0 + lcol] = s - c_o[lcol];
    }
}

extern "C" void kernel_launch(void* const* d_in, const int* in_sizes, int n_in,
                              void* d_out, int out_size, void* d_ws, size_t ws_size,
                              hipStream_t stream) {
    const float* x  = (const float*)d_in[0];
    const float* mu = (const float*)d_in[1];
    const float* ic = (const float*)d_in[2];
    float* out = (float*)d_out;

    gda_mfma<<<dim3(256), dim3(512), 0, stream>>>(x, mu, ic, out);
}